// Round 1
// baseline (1144.672 us; speedup 1.0000x reference)
//
#include <hip/hip_runtime.h>
#include <float.h>

// PretrainingGIN on MI355X — Round 1: correct fp32 baseline.
// Structure: per-call CSR build (counting sort by dst, no float atomics),
// wave-per-node aggregation (h is L3-resident), fused 2-GEMM MLP per layer
// (fp32 vector FMA, LDS-staged activations, L1-broadcast weights),
// binary-search + block-per-graph max pool.
//
// Workspace: 2 x 51.2MB node buffers + 6.4MB CSR + ~1MB misc  (~110 MB).

#define N_NODES 100000
#define N_EDGES 1600000
#define DIM 128
#define NGRAPHS 64

#define SCAN_T 256
#define SCAN_ITEMS 4
#define SCAN_CHUNK 1024                 // SCAN_T * SCAN_ITEMS
#define SCAN_NB ((N_NODES + SCAN_CHUNK - 1) / SCAN_CHUNK)   // 98

#define MROWS 64
#define LDS_STRIDE 68                   // pad: keeps 16B align (mult of 4), breaks most conflicts

__global__ void k_zero_counts(int* __restrict__ counts) {
    int i = blockIdx.x * blockDim.x + threadIdx.x;
    if (i < N_NODES) counts[i] = 0;
}

__global__ void k_hist(const int* __restrict__ dst, int* __restrict__ counts) {
    int e = blockIdx.x * blockDim.x + threadIdx.x;
    if (e < N_EDGES) atomicAdd(&counts[dst[e]], 1);
}

// Block-level exclusive scan, 1024 elems/block; partial offsets + block sums.
__global__ void k_scan1(const int* __restrict__ counts, int* __restrict__ offs,
                        int* __restrict__ bsum) {
    __shared__ int s[SCAN_T];
    int b = blockIdx.x, t = threadIdx.x;
    int base = b * SCAN_CHUNK + t * SCAN_ITEMS;
    int v[SCAN_ITEMS];
    int tot = 0;
#pragma unroll
    for (int j = 0; j < SCAN_ITEMS; ++j) {
        int i = base + j;
        v[j] = (i < N_NODES) ? counts[i] : 0;
        tot += v[j];
    }
    s[t] = tot;
    __syncthreads();
    for (int off = 1; off < SCAN_T; off <<= 1) {
        int x = (t >= off) ? s[t - off] : 0;
        __syncthreads();
        s[t] += x;
        __syncthreads();
    }
    int run = s[t] - tot;   // exclusive prefix of this thread within block
    if (t == SCAN_T - 1) bsum[b] = s[t];
#pragma unroll
    for (int j = 0; j < SCAN_ITEMS; ++j) {
        int i = base + j;
        if (i < N_NODES) offs[i] = run;
        run += v[j];
    }
}

// Exclusive scan of SCAN_NB block sums (single block).
__global__ void k_scan2(int* __restrict__ bsum) {
    __shared__ int s[256];
    int t = threadIdx.x;
    int v = (t < SCAN_NB) ? bsum[t] : 0;
    s[t] = v;
    __syncthreads();
    for (int off = 1; off < 256; off <<= 1) {
        int x = (t >= off) ? s[t - off] : 0;
        __syncthreads();
        s[t] += x;
        __syncthreads();
    }
    if (t < SCAN_NB) bsum[t] = s[t] - v;
}

__global__ void k_scan3(int* __restrict__ offs, int* __restrict__ cursor,
                        const int* __restrict__ bsum) {
    int i = blockIdx.x * blockDim.x + threadIdx.x;
    if (i < N_NODES) {
        int o = offs[i] + bsum[i / SCAN_CHUNK];
        offs[i] = o;
        cursor[i] = o;
    }
    if (i == 0) offs[N_NODES] = N_EDGES;
}

__global__ void k_scatter(const int* __restrict__ src, const int* __restrict__ dst,
                          int* __restrict__ cursor, int* __restrict__ sorted_src) {
    int e = blockIdx.x * blockDim.x + threadIdx.x;
    if (e < N_EDGES) {
        int p = atomicAdd(&cursor[dst[e]], 1);
        sorted_src[p] = src[e];
    }
}

// One wave per node: m[i] = h[i] + sum_{j->i} h[j].  Lane covers 2 cols (float2).
__global__ __launch_bounds__(256) void k_agg(const float* __restrict__ h,
                                             const int* __restrict__ offs,
                                             const int* __restrict__ ssrc,
                                             float* __restrict__ m) {
    int gid = blockIdx.x * blockDim.x + threadIdx.x;
    int w = gid >> 6;
    int lane = gid & 63;
    if (w >= N_NODES) return;
    int col = lane * 2;
    float2 acc = *(const float2*)(h + (size_t)w * DIM + col);
    int e0 = offs[w], e1 = offs[w + 1];
    int e = e0;
    for (; e + 4 <= e1; e += 4) {   // 4 independent row loads in flight
        int s0 = ssrc[e], s1 = ssrc[e + 1], s2 = ssrc[e + 2], s3 = ssrc[e + 3];
        float2 v0 = *(const float2*)(h + (size_t)s0 * DIM + col);
        float2 v1 = *(const float2*)(h + (size_t)s1 * DIM + col);
        float2 v2 = *(const float2*)(h + (size_t)s2 * DIM + col);
        float2 v3 = *(const float2*)(h + (size_t)s3 * DIM + col);
        acc.x += v0.x + v1.x + v2.x + v3.x;
        acc.y += v0.y + v1.y + v2.y + v3.y;
    }
    for (; e < e1; ++e) {
        int s = ssrc[e];
        float2 v = *(const float2*)(h + (size_t)s * DIM + col);
        acc.x += v.x;
        acc.y += v.y;
    }
    *(float2*)(m + (size_t)w * DIM + col) = acc;
}

// Fused MLP: h_out = [relu]( relu(m@W1 + b1) @ W2 + b2 ).  In-place safe
// (each block reads only its own rows into LDS before writing them back).
__global__ __launch_bounds__(256) void k_mlp(const float* m_in, float* h_out,
                                             const float* __restrict__ W1,
                                             const float* __restrict__ b1,
                                             const float* __restrict__ W2,
                                             const float* __restrict__ b2,
                                             int relu_out) {
    __shared__ float lds[DIM][LDS_STRIDE];  // 34 KB; holds m^T, then t^T
    const int t = threadIdx.x;
    const int row0 = blockIdx.x * MROWS;

    // stage m transposed: lds[k][r] = m_in[row0+r][k]
    {
        int r = t >> 2;
        int k0 = (t & 3) * 32;
        int grow = row0 + r;
#pragma unroll
        for (int q = 0; q < 8; ++q) {
            int k = k0 + q * 4;
            float4 v;
            if (grow < N_NODES) v = *(const float4*)(m_in + (size_t)grow * DIM + k);
            else                v = make_float4(0.f, 0.f, 0.f, 0.f);
            lds[k + 0][r] = v.x;
            lds[k + 1][r] = v.y;
            lds[k + 2][r] = v.z;
            lds[k + 3][r] = v.w;
        }
    }
    __syncthreads();

    const int rt = t & 15, ct = t >> 4;
    const int r0 = rt * 4, c0 = ct * 8;

    float acc[4][8];
#pragma unroll
    for (int i = 0; i < 4; ++i)
#pragma unroll
        for (int j = 0; j < 8; ++j) acc[i][j] = 0.f;

    // GEMM1: t = m @ W1
    for (int k = 0; k < DIM; ++k) {
        float4 a = *(const float4*)&lds[k][r0];
        const float* wrow = W1 + k * DIM + c0;
        float4 w0 = *(const float4*)(wrow);
        float4 w1 = *(const float4*)(wrow + 4);
        float av[4] = {a.x, a.y, a.z, a.w};
        float wv[8] = {w0.x, w0.y, w0.z, w0.w, w1.x, w1.y, w1.z, w1.w};
#pragma unroll
        for (int i = 0; i < 4; ++i)
#pragma unroll
            for (int j = 0; j < 8; ++j) acc[i][j] = fmaf(av[i], wv[j], acc[i][j]);
    }
    __syncthreads();   // all reads of m^T done

    // bias + relu, store t transposed back into same LDS
#pragma unroll
    for (int j = 0; j < 8; ++j) {
        float b = b1[c0 + j];
        float4 col;
        col.x = fmaxf(acc[0][j] + b, 0.f);
        col.y = fmaxf(acc[1][j] + b, 0.f);
        col.z = fmaxf(acc[2][j] + b, 0.f);
        col.w = fmaxf(acc[3][j] + b, 0.f);
        *(float4*)&lds[c0 + j][r0] = col;
    }
    __syncthreads();

#pragma unroll
    for (int i = 0; i < 4; ++i)
#pragma unroll
        for (int j = 0; j < 8; ++j) acc[i][j] = 0.f;

    // GEMM2: out = t @ W2
    for (int k = 0; k < DIM; ++k) {
        float4 a = *(const float4*)&lds[k][r0];
        const float* wrow = W2 + k * DIM + c0;
        float4 w0 = *(const float4*)(wrow);
        float4 w1 = *(const float4*)(wrow + 4);
        float av[4] = {a.x, a.y, a.z, a.w};
        float wv[8] = {w0.x, w0.y, w0.z, w0.w, w1.x, w1.y, w1.z, w1.w};
#pragma unroll
        for (int i = 0; i < 4; ++i)
#pragma unroll
            for (int j = 0; j < 8; ++j) acc[i][j] = fmaf(av[i], wv[j], acc[i][j]);
    }

#pragma unroll
    for (int i = 0; i < 4; ++i) {
        int grow = row0 + r0 + i;
        if (grow < N_NODES) {
            float4 o0, o1;
            o0.x = acc[i][0] + b2[c0 + 0];
            o0.y = acc[i][1] + b2[c0 + 1];
            o0.z = acc[i][2] + b2[c0 + 2];
            o0.w = acc[i][3] + b2[c0 + 3];
            o1.x = acc[i][4] + b2[c0 + 4];
            o1.y = acc[i][5] + b2[c0 + 5];
            o1.z = acc[i][6] + b2[c0 + 6];
            o1.w = acc[i][7] + b2[c0 + 7];
            if (relu_out) {
                o0.x = fmaxf(o0.x, 0.f); o0.y = fmaxf(o0.y, 0.f);
                o0.z = fmaxf(o0.z, 0.f); o0.w = fmaxf(o0.w, 0.f);
                o1.x = fmaxf(o1.x, 0.f); o1.y = fmaxf(o1.y, 0.f);
                o1.z = fmaxf(o1.z, 0.f); o1.w = fmaxf(o1.w, 0.f);
            }
            *(float4*)(h_out + (size_t)grow * DIM + c0) = o0;
            *(float4*)(h_out + (size_t)grow * DIM + c0 + 4) = o1;
        }
    }
}

// batch is sorted: starts[g] = lower_bound(batch, g), g in [0, 64].
__global__ void k_starts(const int* __restrict__ batch, int* __restrict__ starts) {
    int g = threadIdx.x;
    if (g > NGRAPHS) return;
    int lo = 0, hi = N_NODES;
    while (lo < hi) {
        int mid = (lo + hi) >> 1;
        if (batch[mid] < g) lo = mid + 1;
        else hi = mid;
    }
    starts[g] = lo;
}

__global__ void k_pool(const float* __restrict__ h, const int* __restrict__ starts,
                       float* __restrict__ out) {
    int g = blockIdx.x;
    int c = threadIdx.x;   // 128 threads = 128 cols
    int i0 = starts[g], i1 = starts[g + 1];
    float m0 = -FLT_MAX, m1 = -FLT_MAX, m2 = -FLT_MAX, m3 = -FLT_MAX;
    int i = i0;
    for (; i + 4 <= i1; i += 4) {
        m0 = fmaxf(m0, h[(size_t)(i + 0) * DIM + c]);
        m1 = fmaxf(m1, h[(size_t)(i + 1) * DIM + c]);
        m2 = fmaxf(m2, h[(size_t)(i + 2) * DIM + c]);
        m3 = fmaxf(m3, h[(size_t)(i + 3) * DIM + c]);
    }
    for (; i < i1; ++i) m0 = fmaxf(m0, h[(size_t)i * DIM + c]);
    out[g * DIM + c] = fmaxf(fmaxf(m0, m1), fmaxf(m2, m3));
}

extern "C" void kernel_launch(void* const* d_in, const int* in_sizes, int n_in,
                              void* d_out, int out_size, void* d_ws, size_t ws_size,
                              hipStream_t stream) {
    const float* x   = (const float*)d_in[0];
    const int* ei    = (const int*)d_in[1];
    const int* batch = (const int*)d_in[2];
    const float* W1  = (const float*)d_in[3];
    const float* b1  = (const float*)d_in[4];
    const float* W2  = (const float*)d_in[5];
    const float* b2  = (const float*)d_in[6];
    float* out = (float*)d_out;

    const int* src = ei;             // edge_index[0]
    const int* dst = ei + N_EDGES;   // edge_index[1]

    float* bufA     = (float*)d_ws;                      // 51.2 MB
    float* bufB     = bufA + (size_t)N_NODES * DIM;      // 51.2 MB
    int* sorted_src = (int*)(bufB + (size_t)N_NODES * DIM);  // 6.4 MB
    int* offs       = sorted_src + N_EDGES;              // N_NODES+1
    int* cursor     = offs + (N_NODES + 1);              // N_NODES (also counts)
    int* bsum       = cursor + N_NODES;                  // SCAN_NB
    int* starts     = bsum + SCAN_NB;                    // NGRAPHS+1

    // ---- CSR build (once per call; ws is re-poisoned every call) ----
    k_zero_counts<<<(N_NODES + 255) / 256, 256, 0, stream>>>(cursor);
    k_hist<<<(N_EDGES + 255) / 256, 256, 0, stream>>>(dst, cursor);
    k_scan1<<<SCAN_NB, SCAN_T, 0, stream>>>(cursor, offs, bsum);
    k_scan2<<<1, 256, 0, stream>>>(bsum);
    k_scan3<<<(N_NODES + 255) / 256, 256, 0, stream>>>(offs, cursor, bsum);
    k_scatter<<<(N_EDGES + 255) / 256, 256, 0, stream>>>(src, dst, cursor, sorted_src);

    const int aggBlocks = N_NODES / 4;                       // 4 waves/block
    const int mlpBlocks = (N_NODES + MROWS - 1) / MROWS;

    // layer 0: x -> bufA
    k_agg<<<aggBlocks, 256, 0, stream>>>(x, offs, sorted_src, bufA);
    k_mlp<<<mlpBlocks, 256, 0, stream>>>(bufA, bufA, W1, b1, W2, b2, 1);
    // layer 1: bufA -> bufB
    k_agg<<<aggBlocks, 256, 0, stream>>>(bufA, offs, sorted_src, bufB);
    k_mlp<<<mlpBlocks, 256, 0, stream>>>(bufB, bufB, W1 + DIM * DIM, b1 + DIM,
                                         W2 + DIM * DIM, b2 + DIM, 1);
    // layer 2: bufB -> bufA (no trailing relu)
    k_agg<<<aggBlocks, 256, 0, stream>>>(bufB, offs, sorted_src, bufA);
    k_mlp<<<mlpBlocks, 256, 0, stream>>>(bufA, bufA, W1 + 2 * DIM * DIM, b1 + 2 * DIM,
                                         W2 + 2 * DIM * DIM, b2 + 2 * DIM, 0);

    // ---- global max pool ----
    k_starts<<<1, 128, 0, stream>>>(batch, starts);
    k_pool<<<NGRAPHS, DIM, 0, stream>>>(bufA, starts, out);
}

// Round 2
// 701.562 us; speedup vs baseline: 1.6316x; 1.6316x over previous
//
#include <hip/hip_runtime.h>
#include <float.h>

// PretrainingGIN on MI355X — Round 2: bf16-MFMA MLP, bf16 node features.
// - CSR build (counting sort by dst) unchanged.
// - k_agg: wave/node gather-sum in fp32 acc over bf16 rows (halved traffic).
// - k_mlp: fused 2-GEMM MLP on v_mfma_f32_16x16x32_bf16. A-frags load 16B
//   contiguous from row-major m; B repacked per-call into fragment order;
//   GEMM1->GEMM2 transpose via wave-private LDS rows (no barrier);
//   single __syncthreads before coalesced bf16x8 store-back. In-place safe.
// - k_pool: block/graph, 4-way row-parallel fp32 max over bf16.

#define N_NODES 100000
#define N_EDGES 1600000
#define DIM 128
#define NGRAPHS 64

#define SCAN_T 256
#define SCAN_ITEMS 4
#define SCAN_CHUNK 1024
#define SCAN_NB ((N_NODES + SCAN_CHUNK - 1) / SCAN_CHUNK)   // 98

#define MROWS 128          // rows per MLP block (2 row-tiles of 64)
#define LSTRIDE 136        // bf16 elems; 272B rows keep 16B align

typedef __attribute__((ext_vector_type(8))) short bf16x8;
typedef __attribute__((ext_vector_type(4))) float f32x4;

__device__ inline float bflo(unsigned u) { return __uint_as_float(u << 16); }
__device__ inline float bfhi(unsigned u) { return __uint_as_float(u & 0xffff0000u); }

__device__ inline unsigned short f2bf(float a) {      // RNE
    unsigned u = __float_as_uint(a);
    u = u + 0x7fff + ((u >> 16) & 1);
    return (unsigned short)(u >> 16);
}
__device__ inline unsigned f2bf_pack(float a, float b) {
    unsigned ua = __float_as_uint(a), ub = __float_as_uint(b);
    ua = ua + 0x7fff + ((ua >> 16) & 1);
    ub = ub + 0x7fff + ((ub >> 16) & 1);
    return (ua >> 16) | (ub & 0xffff0000u);
}

// ---------------- CSR build ----------------
__global__ void k_zero_counts(int* __restrict__ counts) {
    int i = blockIdx.x * blockDim.x + threadIdx.x;
    if (i < N_NODES) counts[i] = 0;
}

__global__ void k_hist(const int* __restrict__ dst, int* __restrict__ counts) {
    int e = blockIdx.x * blockDim.x + threadIdx.x;
    if (e < N_EDGES) atomicAdd(&counts[dst[e]], 1);
}

__global__ void k_scan1(const int* __restrict__ counts, int* __restrict__ offs,
                        int* __restrict__ bsum) {
    __shared__ int s[SCAN_T];
    int b = blockIdx.x, t = threadIdx.x;
    int base = b * SCAN_CHUNK + t * SCAN_ITEMS;
    int v[SCAN_ITEMS];
    int tot = 0;
#pragma unroll
    for (int j = 0; j < SCAN_ITEMS; ++j) {
        int i = base + j;
        v[j] = (i < N_NODES) ? counts[i] : 0;
        tot += v[j];
    }
    s[t] = tot;
    __syncthreads();
    for (int off = 1; off < SCAN_T; off <<= 1) {
        int x = (t >= off) ? s[t - off] : 0;
        __syncthreads();
        s[t] += x;
        __syncthreads();
    }
    int run = s[t] - tot;
    if (t == SCAN_T - 1) bsum[b] = s[t];
#pragma unroll
    for (int j = 0; j < SCAN_ITEMS; ++j) {
        int i = base + j;
        if (i < N_NODES) offs[i] = run;
        run += v[j];
    }
}

__global__ void k_scan2(int* __restrict__ bsum) {
    __shared__ int s[256];
    int t = threadIdx.x;
    int v = (t < SCAN_NB) ? bsum[t] : 0;
    s[t] = v;
    __syncthreads();
    for (int off = 1; off < 256; off <<= 1) {
        int x = (t >= off) ? s[t - off] : 0;
        __syncthreads();
        s[t] += x;
        __syncthreads();
    }
    if (t < SCAN_NB) bsum[t] = s[t] - v;
}

__global__ void k_scan3(int* __restrict__ offs, int* __restrict__ cursor,
                        const int* __restrict__ bsum) {
    int i = blockIdx.x * blockDim.x + threadIdx.x;
    if (i < N_NODES) {
        int o = offs[i] + bsum[i / SCAN_CHUNK];
        offs[i] = o;
        cursor[i] = o;
    }
    if (i == 0) offs[N_NODES] = N_EDGES;
}

__global__ void k_scatter(const int* __restrict__ src, const int* __restrict__ dst,
                          int* __restrict__ cursor, int* __restrict__ sorted_src) {
    int e = blockIdx.x * blockDim.x + threadIdx.x;
    if (e < N_EDGES) {
        int p = atomicAdd(&cursor[dst[e]], 1);
        sorted_src[p] = src[e];
    }
}

// ---------------- dtype prep ----------------
__global__ void k_cast(const float* __restrict__ x, unsigned short* __restrict__ y) {
    int i = (blockIdx.x * blockDim.x + threadIdx.x) * 4;
    if (i < N_NODES * DIM) {
        float4 v = *(const float4*)(x + i);
        uint2 o;
        o.x = f2bf_pack(v.x, v.y);
        o.y = f2bf_pack(v.z, v.w);
        *(uint2*)(y + i) = o;
    }
}

// Repack W (k-major 128x128 fp32) into B-fragment order bf16:
// pack[mat][kb*4096 + c*32 + q*8 + j] = W[mat][(kb*32 + q*8 + j)*128 + c]
__global__ void k_pack(const float* __restrict__ W1, const float* __restrict__ W2,
                       unsigned short* __restrict__ pack) {
    int tid = blockIdx.x * blockDim.x + threadIdx.x;
    if (tid >= 6 * DIM * DIM) return;
    int mat = tid >> 14;           // 0..5 : W1 l0..2, W2 l0..2
    int e = tid & 16383;
    int k = e >> 7, c = e & 127;
    const float* W = (mat < 3) ? (W1 + mat * DIM * DIM) : (W2 + (mat - 3) * DIM * DIM);
    int kb = k >> 5, q = (k >> 3) & 3, j = k & 7;
    pack[mat * DIM * DIM + kb * 4096 + c * 32 + q * 8 + j] = f2bf(W[k * DIM + c]);
}

// ---------------- aggregation: m[i] = h[i] + sum_{j->i} h[j] ----------------
__global__ __launch_bounds__(256) void k_agg(const unsigned short* __restrict__ h,
                                             const int* __restrict__ offs,
                                             const int* __restrict__ ssrc,
                                             unsigned short* __restrict__ m) {
    int gid = blockIdx.x * blockDim.x + threadIdx.x;
    int w = gid >> 6;
    int lane = gid & 63;
    if (w >= N_NODES) return;
    int col = lane * 2;
    size_t rb = (size_t)w * DIM + col;
    unsigned u = *(const unsigned*)(h + rb);
    float ax = bflo(u), ay = bfhi(u);
    int e0 = offs[w], e1 = offs[w + 1];
    int e = e0;
    for (; e + 4 <= e1; e += 4) {
        int s0 = ssrc[e], s1 = ssrc[e + 1], s2 = ssrc[e + 2], s3 = ssrc[e + 3];
        unsigned v0 = *(const unsigned*)(h + (size_t)s0 * DIM + col);
        unsigned v1 = *(const unsigned*)(h + (size_t)s1 * DIM + col);
        unsigned v2 = *(const unsigned*)(h + (size_t)s2 * DIM + col);
        unsigned v3 = *(const unsigned*)(h + (size_t)s3 * DIM + col);
        ax += bflo(v0) + bflo(v1) + bflo(v2) + bflo(v3);
        ay += bfhi(v0) + bfhi(v1) + bfhi(v2) + bfhi(v3);
    }
    for (; e < e1; ++e) {
        unsigned v = *(const unsigned*)(h + (size_t)ssrc[e] * DIM + col);
        ax += bflo(v);
        ay += bfhi(v);
    }
    *(unsigned*)(m + rb) = f2bf_pack(ax, ay);
}

// ---------------- fused MLP on MFMA ----------------
// h_out = [relu]( relu(m@W1 + b1) @ W2 + b2 ), in-place safe per block.
__global__ __launch_bounds__(256) void k_mlp(const unsigned short* __restrict__ m,
                                             unsigned short* __restrict__ hout,
                                             const unsigned short* __restrict__ Wp1,
                                             const float* __restrict__ b1,
                                             const unsigned short* __restrict__ Wp2,
                                             const float* __restrict__ b2,
                                             int relu_out) {
    __shared__ unsigned short t1[MROWS * LSTRIDE];   // 34816 B
    const int tid = threadIdx.x;
    const int wv = tid >> 6, lane = tid & 63;
    const int q = lane >> 4, n = lane & 15;
    const int row0 = blockIdx.x * MROWS;

    // A1 fragments: 2 row-tiles x 4 k-blocks, each 16B contiguous from global m
    bf16x8 a1[2][4];
#pragma unroll
    for (int s = 0; s < 2; ++s) {
        int grow = row0 + s * 64 + wv * 16 + n;
        if (grow >= N_NODES) grow = N_NODES - 1;   // stores masked later
        const unsigned short* mr = m + (size_t)grow * DIM + q * 8;
#pragma unroll
        for (int kb = 0; kb < 4; ++kb)
            a1[s][kb] = *(const bf16x8*)(mr + kb * 32);
    }

    float bia1[8], bia2[8];
#pragma unroll
    for (int ct = 0; ct < 8; ++ct) {
        bia1[ct] = b1[ct * 16 + n];
        bia2[ct] = b2[ct * 16 + n];
    }

    // GEMM1: t = relu(m@W1 + b1) -> LDS (wave-private rows; no barrier needed)
#pragma unroll
    for (int ct = 0; ct < 8; ++ct) {
        f32x4 acc0 = {0.f, 0.f, 0.f, 0.f};
        f32x4 acc1 = {0.f, 0.f, 0.f, 0.f};
#pragma unroll
        for (int kb = 0; kb < 4; ++kb) {
            bf16x8 b = *(const bf16x8*)(Wp1 + kb * 4096 + (ct * 16 + n) * 32 + q * 8);
            acc0 = __builtin_amdgcn_mfma_f32_16x16x32_bf16(a1[0][kb], b, acc0, 0, 0, 0);
            acc1 = __builtin_amdgcn_mfma_f32_16x16x32_bf16(a1[1][kb], b, acc1, 0, 0, 0);
        }
#pragma unroll
        for (int r = 0; r < 4; ++r) {
            int lr = wv * 16 + q * 4 + r;
            t1[lr * LSTRIDE + ct * 16 + n]        = f2bf(fmaxf(acc0[r] + bia1[ct], 0.f));
            t1[(64 + lr) * LSTRIDE + ct * 16 + n] = f2bf(fmaxf(acc1[r] + bia1[ct], 0.f));
        }
    }

    // A2 fragments from LDS (same wave's rows; compiler orders via lgkmcnt)
    bf16x8 a2[2][4];
#pragma unroll
    for (int s = 0; s < 2; ++s) {
        const unsigned short* tr = t1 + (s * 64 + wv * 16 + n) * LSTRIDE + q * 8;
#pragma unroll
        for (int kb = 0; kb < 4; ++kb)
            a2[s][kb] = *(const bf16x8*)(tr + kb * 32);
    }

    // GEMM2: out = t@W2 + b2 -> back into t1 (wave-private rows)
#pragma unroll
    for (int ct = 0; ct < 8; ++ct) {
        f32x4 acc0 = {0.f, 0.f, 0.f, 0.f};
        f32x4 acc1 = {0.f, 0.f, 0.f, 0.f};
#pragma unroll
        for (int kb = 0; kb < 4; ++kb) {
            bf16x8 b = *(const bf16x8*)(Wp2 + kb * 4096 + (ct * 16 + n) * 32 + q * 8);
            acc0 = __builtin_amdgcn_mfma_f32_16x16x32_bf16(a2[0][kb], b, acc0, 0, 0, 0);
            acc1 = __builtin_amdgcn_mfma_f32_16x16x32_bf16(a2[1][kb], b, acc1, 0, 0, 0);
        }
#pragma unroll
        for (int r = 0; r < 4; ++r) {
            int lr = wv * 16 + q * 4 + r;
            float v0 = acc0[r] + bia2[ct];
            float v1 = acc1[r] + bia2[ct];
            if (relu_out) { v0 = fmaxf(v0, 0.f); v1 = fmaxf(v1, 0.f); }
            t1[lr * LSTRIDE + ct * 16 + n]        = f2bf(v0);
            t1[(64 + lr) * LSTRIDE + ct * 16 + n] = f2bf(v1);
        }
    }
    __syncthreads();

    // coalesced store-back: thread -> row tid>>1, 64-col half (tid&1)
    {
        int r = tid >> 1;
        int c0 = (tid & 1) * 64;
        int grow = row0 + r;
        if (grow < N_NODES) {
            unsigned short* dp = hout + (size_t)grow * DIM + c0;
            const unsigned short* sp = t1 + r * LSTRIDE + c0;
#pragma unroll
            for (int s8 = 0; s8 < 8; ++s8)
                *(bf16x8*)(dp + s8 * 8) = *(const bf16x8*)(sp + s8 * 8);
        }
    }
}

// ---------------- pool ----------------
__global__ void k_starts(const int* __restrict__ batch, int* __restrict__ starts) {
    int g = threadIdx.x;
    if (g > NGRAPHS) return;
    int lo = 0, hi = N_NODES;
    while (lo < hi) {
        int mid = (lo + hi) >> 1;
        if (batch[mid] < g) lo = mid + 1;
        else hi = mid;
    }
    starts[g] = lo;
}

__global__ __launch_bounds__(256) void k_pool(const unsigned short* __restrict__ h,
                                              const int* __restrict__ starts,
                                              float* __restrict__ out) {
    __shared__ float red[4][DIM];
    int g = blockIdx.x;
    int t = threadIdx.x;
    int rowpar = t >> 6;           // 0..3
    int col = (t & 63) * 2;
    int i0 = starts[g], i1 = starts[g + 1];
    float mx = -FLT_MAX, my = -FLT_MAX;
    for (int i = i0 + rowpar; i < i1; i += 4) {
        unsigned u = *(const unsigned*)(h + (size_t)i * DIM + col);
        mx = fmaxf(mx, bflo(u));
        my = fmaxf(my, bfhi(u));
    }
    red[rowpar][col] = mx;
    red[rowpar][col + 1] = my;
    __syncthreads();
    if (rowpar == 0) {
        mx = fmaxf(fmaxf(red[0][col], red[1][col]), fmaxf(red[2][col], red[3][col]));
        my = fmaxf(fmaxf(red[0][col + 1], red[1][col + 1]),
                   fmaxf(red[2][col + 1], red[3][col + 1]));
        out[g * DIM + col] = mx;
        out[g * DIM + col + 1] = my;
    }
}

extern "C" void kernel_launch(void* const* d_in, const int* in_sizes, int n_in,
                              void* d_out, int out_size, void* d_ws, size_t ws_size,
                              hipStream_t stream) {
    const float* x   = (const float*)d_in[0];
    const int* ei    = (const int*)d_in[1];
    const int* batch = (const int*)d_in[2];
    const float* W1  = (const float*)d_in[3];
    const float* b1  = (const float*)d_in[4];
    const float* W2  = (const float*)d_in[5];
    const float* b2  = (const float*)d_in[6];
    float* out = (float*)d_out;

    const int* src = ei;
    const int* dst = ei + N_EDGES;

    unsigned short* hA   = (unsigned short*)d_ws;                 // 25.6 MB
    unsigned short* hB   = hA + (size_t)N_NODES * DIM;            // 25.6 MB
    unsigned short* wpk  = hB + (size_t)N_NODES * DIM;            // 192 KB
    int* sorted_src = (int*)(wpk + 6 * DIM * DIM);                // 6.4 MB
    int* offs       = sorted_src + N_EDGES;
    int* cursor     = offs + (N_NODES + 1);
    int* bsum       = cursor + N_NODES;
    int* starts     = bsum + SCAN_NB;

    // CSR build
    k_zero_counts<<<(N_NODES + 255) / 256, 256, 0, stream>>>(cursor);
    k_hist<<<(N_EDGES + 255) / 256, 256, 0, stream>>>(dst, cursor);
    k_scan1<<<SCAN_NB, SCAN_T, 0, stream>>>(cursor, offs, bsum);
    k_scan2<<<1, 256, 0, stream>>>(bsum);
    k_scan3<<<(N_NODES + 255) / 256, 256, 0, stream>>>(offs, cursor, bsum);
    k_scatter<<<(N_EDGES + 255) / 256, 256, 0, stream>>>(src, dst, cursor, sorted_src);

    // dtype prep
    k_cast<<<(N_NODES * DIM / 4 + 255) / 256, 256, 0, stream>>>(x, hA);
    k_pack<<<(6 * DIM * DIM + 255) / 256, 256, 0, stream>>>(W1, W2, wpk);

    const int aggBlocks = N_NODES / 4;       // wave per node
    const int mlpBlocks = (N_NODES + MROWS - 1) / MROWS;

    unsigned short* Wp1 = wpk;               // W1 layers 0..2
    unsigned short* Wp2 = wpk + 3 * DIM * DIM;

    // layer 0: hA -> m=hB -> h=hB
    k_agg<<<aggBlocks, 256, 0, stream>>>(hA, offs, sorted_src, hB);
    k_mlp<<<mlpBlocks, 256, 0, stream>>>(hB, hB, Wp1, b1, Wp2, b2, 1);
    // layer 1: hB -> m=hA -> h=hA
    k_agg<<<aggBlocks, 256, 0, stream>>>(hB, offs, sorted_src, hA);
    k_mlp<<<mlpBlocks, 256, 0, stream>>>(hA, hA, Wp1 + DIM * DIM, b1 + DIM,
                                         Wp2 + DIM * DIM, b2 + DIM, 1);
    // layer 2: hA -> m=hB -> h=hB (no trailing relu)
    k_agg<<<aggBlocks, 256, 0, stream>>>(hA, offs, sorted_src, hB);
    k_mlp<<<mlpBlocks, 256, 0, stream>>>(hB, hB, Wp1 + 2 * DIM * DIM, b1 + 2 * DIM,
                                         Wp2 + 2 * DIM * DIM, b2 + 2 * DIM, 0);

    // pool
    k_starts<<<1, 128, 0, stream>>>(batch, starts);
    k_pool<<<NGRAPHS, 256, 0, stream>>>(hB, starts, out);
}